// Round 8
// baseline (171.347 us; speedup 1.0000x reference)
//
#include <hip/hip_runtime.h>
#include <hip/hip_bf16.h>
#include <math.h>

typedef __bf16 bf16x8 __attribute__((ext_vector_type(8)));
typedef float f32x4 __attribute__((ext_vector_type(4)));
typedef unsigned int u32;
typedef u32 u32x4 __attribute__((ext_vector_type(4)));
typedef u32 u32x2 __attribute__((ext_vector_type(2)));

// Problem constants: B=8, C=256, H=W=64, O=256, K=9, GN groups=32 (8 ch each)
// xT layout (granule-major): [b][cg=32][pix=4096][8ch] bf16; granule = 16B.

__device__ inline u32 pack2bf16(float a, float b) {
  u32 ua = __float_as_uint(a);
  u32 ub = __float_as_uint(b);
  ua += 0x7fffu + ((ua >> 16) & 1u);   // RNE
  ub += 0x7fffu + ((ub >> 16) & 1u);
  return (ua >> 16) | (ub & 0xffff0000u);
}

// ---------------------------------------------------------------------------
// K0: prep — pack w_dcn into swizzled bf16 tiles, pack w_off into swizzled
// bf16 tiles (O padded 18->32), zero stats.
// ---------------------------------------------------------------------------
__global__ void prep(const float* __restrict__ w_dcn, const float* __restrict__ w_off,
                     unsigned short* __restrict__ wT4, unsigned short* __restrict__ wOffT,
                     float* __restrict__ stats) {
  size_t id = (size_t)blockIdx.x * 256 + threadIdx.x;
  if (id < 589824) {               // 256 o * 2304 ck
    int o  = (int)(id / 2304);
    int ck = (int)(id % 2304);     // ck = k*256 + c
    int k = ck >> 8, c = ck & 255;
    float v = w_dcn[(size_t)(o * 256 + c) * 9 + k];
    u32 uv = __float_as_uint(v);
    uv += 0x7fffu + ((uv >> 16) & 1u);
    int tile = ck >> 6, kk = ck & 63;
    int lin = o * 128 + kk * 2;
    int swz = lin ^ ((o & 7) << 4);
    *(unsigned short*)((char*)wT4 + (size_t)tile * 32768 + swz) = (unsigned short)(uv >> 16);
  } else if (id < 663552) {        // 36 tiles * 32 o * 64 kk = 73728
    int r = (int)(id - 589824);
    int tile = r >> 11;            // k*4 + cc
    int rr = r & 2047;
    int o = rr >> 6, kk = rr & 63;
    int k = tile >> 2, cc = tile & 3;
    int c = (cc << 6) + kk;
    float v = (o < 18) ? w_off[(size_t)(o * 256 + c) * 9 + k] : 0.f;
    u32 uv = __float_as_uint(v);
    uv += 0x7fffu + ((uv >> 16) & 1u);
    int swz = (o * 128 + kk * 2) ^ ((o & 7) << 4);
    *(unsigned short*)((char*)wOffT + (size_t)tile * 4096 + swz) = (unsigned short)(uv >> 16);
  } else if (id < 664064) {        // zero stats: 512 floats
    stats[id - 663552] = 0.f;
  }
}

// ---------------------------------------------------------------------------
// K1: transpose x [B][C][H][W] -> xT granule-major [b][cg][pix][8ch] bf16
// ---------------------------------------------------------------------------
__global__ __launch_bounds__(256) void transpose_x(const float* __restrict__ x,
                                                   unsigned short* __restrict__ xT) {
  __shared__ float tl[64][65];
  int bx = blockIdx.x;
  int b = bx >> 8;
  int y = (bx >> 2) & 63;
  int cb = (bx & 3) << 6;          // 64-ch chunk base
  int t = threadIdx.x;
  int xi = t & 63, cr = t >> 6;
  size_t base = (((size_t)(b * 256 + cb) * 64 + y) << 6);
#pragma unroll
  for (int rep = 0; rep < 16; ++rep) {
    int cl = rep * 4 + cr;
    tl[cl][xi] = x[base + (size_t)cl * 4096 + xi];
  }
  __syncthreads();
  int xw = t & 63, cpair = t >> 6;   // cpair in [0,4)
#pragma unroll
  for (int r = 0; r < 2; ++r) {
    int cgl = cpair * 2 + r;         // local granule in this 64-ch chunk
    int cg = (cb >> 3) + cgl;
    u32 pk4[4];
#pragma unroll
    for (int i = 0; i < 4; ++i)
      pk4[i] = pack2bf16(tl[cgl * 8 + 2 * i][xw], tl[cgl * 8 + 2 * i + 1][xw]);
    u32x4 v = {pk4[0], pk4[1], pk4[2], pk4[3]};
    *(u32x4*)((char*)xT + (((size_t)b << 21)) + ((size_t)cg << 16) + ((y << 6) + xw) * 16) = v;
  }
}

// ---------------------------------------------------------------------------
// K2: offset conv via MFMA (unchanged from R7).
// ---------------------------------------------------------------------------
__global__ __launch_bounds__(512, 2) void conv_offset_mfma(
    const unsigned short* __restrict__ xT, const unsigned short* __restrict__ wOffT,
    float* __restrict__ offs) {
  __shared__ unsigned short A[2][128][64]; // 32KB, byte ^= (row&7)<<4
  __shared__ unsigned short Bo[2][2048];   // 8KB  ([32 o][64 kk], swizzled)
  const int bx = blockIdx.x;
  const int lb = ((bx & 7) << 5) + (bx >> 3);   // XCD x -> image x
  const int b = lb >> 5;
  const int rp = lb & 31;          // row pair
  const int t = threadIdx.x;
  const int lane = t & 63, wid = t >> 6;   // wid 0..7
  const char* xTbB = (const char*)xT + ((size_t)b << 21);
  const int p = t >> 2;            // local pixel 0..127
  const int row = (rp << 1) + (p >> 6);
  const int xx = p & 63;
  const int cpl = (t & 3) << 1;    // granule-pair slot within cc-chunk

  f32x4 acc[2];
  {
    f32x4 z = {0.f, 0.f, 0.f, 0.f};
    acc[0] = z; acc[1] = z;
  }

  u32x4 ra = {0u,0u,0u,0u}, rb = {0u,0u,0u,0u};

  auto issue = [&](int tt, int d) {
    int k = tt >> 2, cc = tt & 3;
    int ky = k / 3, kx = k - ky * 3;
    int ys = row - 1 + ky;
    int xs = xx - 1 + kx;
    bool ok = ((unsigned)ys < 64u) && ((unsigned)xs < 64u);
    u32x4 z = {0u,0u,0u,0u};
    ra = z; rb = z;
    if (ok) {
      const char* s0 = xTbB + ((size_t)(cc * 8 + cpl) << 16) + (((ys << 6) + xs) << 4);
      ra = *(const u32x4*)s0;
      rb = *(const u32x4*)(s0 + 65536);
    }
    if (wid < 4)
      __builtin_amdgcn_global_load_lds(
          (const __attribute__((address_space(1))) u32*)((const char*)wOffT + ((size_t)tt << 12) + (wid << 10) + (lane << 4)),
          (__attribute__((address_space(3))) u32*)((char*)&Bo[d][0] + (wid << 10)),
          16, 0, 0);
  };
  auto writeA = [&](int d) {
    char* dst = (char*)&A[d][0][0] + p * 128;
    int b0 = (t & 3) << 5;
    int sw = (p & 7) << 4;
    *(u32x4*)(dst + (b0 ^ sw)) = ra;
    *(u32x4*)(dst + ((b0 + 16) ^ sw)) = rb;
  };

  issue(0, 0);
  writeA(0);
  __syncthreads();

  int cur = 0;
  for (int tt = 0; tt < 36; ++tt) {
    if (tt < 35) issue(tt + 1, cur ^ 1);
#pragma unroll
    for (int s = 0; s < 2; ++s) {
      int r16 = (wid << 4) + (lane & 15);
      int kx = (s << 6) + ((lane >> 4) << 4);
      bf16x8 a = *(const bf16x8*)((const char*)&A[cur][0][0] + r16 * 128 + (kx ^ ((r16 & 7) << 4)));
#pragma unroll
      for (int j = 0; j < 2; ++j) {
        int o = (j << 4) + (lane & 15);
        bf16x8 bv = *(const bf16x8*)((const char*)&Bo[cur][0] + o * 128 + (kx ^ ((o & 7) << 4)));
        acc[j] = __builtin_amdgcn_mfma_f32_16x16x32_bf16(a, bv, acc[j], 0, 0, 0);
      }
    }
    if (tt < 35) writeA(cur ^ 1);
    __syncthreads();
    cur ^= 1;
  }

#pragma unroll
  for (int j = 0; j < 2; ++j) {
    int o = (j << 4) + (lane & 15);
    if (o < 18) {
#pragma unroll
      for (int r = 0; r < 4; ++r) {
        int pl = (wid << 4) + ((lane >> 4) << 2) + r;
        offs[((size_t)b * 4096 + (rp << 7) + pl) * 18 + o] = acc[j][r];
      }
    }
  }
}

// ---------------------------------------------------------------------------
// K4: main fused kernel — 2 BLOCKS/CU (anti-phased barrier domains).
// block = 64 px x 256 O, 512 thr: waves 0-3 consumers (o-split, acc[4][4]);
// waves 4-7 producers (px = lane, 2 granules/thread). LDS exactly 80KiB ->
// 2 blocks/CU. Params recomputed per-k into producer registers (no LDS).
// ---------------------------------------------------------------------------
union Arena {
  struct {
    unsigned short A[2][64][64];    //  16,384 B (byte ^= (row&7)<<4)
    unsigned short Bt[2][16384];    //  65,536 B ([256 o][64 kk] swz)
  } m;
  unsigned short ytile[256][72];    //  36,864 B (o-major epilogue buffer)
};

__global__ __launch_bounds__(512, 4) void dcn_main(
    const unsigned short* __restrict__ xT, const float* __restrict__ offs,
    const float* __restrict__ boff, const unsigned short* __restrict__ wT4,
    unsigned short* __restrict__ yb, float* __restrict__ stats) {
  __shared__ Arena ar;

  const int bx = blockIdx.x;
  const int lb = ((bx & 7) << 6) + (bx >> 3);   // XCD x -> image x
  const int b = lb >> 6;
  const int pxbase = (lb & 63) << 6;            // 64-px group (one row)
  const int t = threadIdx.x;
  const int lane = t & 63, wid = t >> 6;        // wid 0..7
  const bool is_cons = (wid < 4);
  const int obase = (wid & 3) << 6;             // consumer o-block
  const char* xTbB = (const char*)xT + ((size_t)b << 21);

  // producer mapping: px = lane (coalesced); granules g0 = (wid-4)*2, g0+1
  const int wp = wid & 3;                       // producer wave index
  const int g0 = wp << 1;

  f32x4 acc[4][4];
#pragma unroll
  for (int i = 0; i < 4; ++i)
#pragma unroll
    for (int j = 0; j < 4; ++j) {
      f32x4 z = {0.f, 0.f, 0.f, 0.f};
      acc[i][j] = z;
    }

  // --- producer param compute (registers; px = lane) ---
  auto cparams = [&](int k, u32& c01, u32& c23, f32x4& w4) {
    int pxg = pxbase + lane;
    int yy = pxg >> 6, xx = pxg & 63;
    int ky = k / 3, kx = k - ky * 3;
    const float* op = offs + ((size_t)b * 4096 + pxg) * 18 + k * 2;
    float py = op[0] + boff[k * 2] + (float)(yy - 1 + ky);
    float pxf = op[1] + boff[k * 2 + 1] + (float)(xx - 1 + kx);
    float fy = floorf(py), fx = floorf(pxf);
    float dy = py - fy, dx = pxf - fx;
    int y0 = (int)fy, x0 = (int)fx;
    int y1 = y0 + 1, x1 = x0 + 1;
    float vy0 = ((unsigned)y0 < 64u) ? 1.f : 0.f;
    float vy1 = ((unsigned)y1 < 64u) ? 1.f : 0.f;
    float vx0 = ((unsigned)x0 < 64u) ? 1.f : 0.f;
    float vx1 = ((unsigned)x1 < 64u) ? 1.f : 0.f;
    int y0c = min(max(y0, 0), 63), y1c = min(max(y1, 0), 63);
    int x0c = min(max(x0, 0), 63), x1c = min(max(x1, 0), 63);
    u32 c0 = (u32)((y0c << 6) + x0c), c1 = (u32)((y0c << 6) + x1c);
    u32 c2 = (u32)((y1c << 6) + x0c), c3 = (u32)((y1c << 6) + x1c);
    c01 = c0 | (c1 << 16);
    c23 = c2 | (c3 << 16);
    w4[0] = (1.f - dy) * (1.f - dx) * vy0 * vx0;
    w4[1] = (1.f - dy) * dx * vy0 * vx1;
    w4[2] = dy * (1.f - dx) * vy1 * vx0;
    w4[3] = dy * dx * vy1 * vx1;
  };

  // --- producer stage: tile (tt = k*4+cc) into buffer d ---
  auto stage = [&](int tt, int cc, int d, u32 c01, u32 c23, f32x4 w4) {
    // B: async global->LDS, 8KB per producer wave
    {
      const char* src = (const char*)wT4 + ((size_t)tt << 15) + (wp << 13);
      char* dstb = (char*)&ar.m.Bt[d][0] + (wp << 13);
#pragma unroll
      for (int i2 = 0; i2 < 8; ++i2) {
        __builtin_amdgcn_global_load_lds(
            (const __attribute__((address_space(1))) u32*)(src + (i2 << 10) + (lane << 4)),
            (__attribute__((address_space(3))) u32*)(dstb + (i2 << 10)),
            16, 0, 0);
      }
    }
    // A: sample 2 granules x 4 corners, blend, pack, swizzled LDS write
    const char* base = xTbB + ((size_t)((cc << 3) + g0) << 16);
    const char* s0 = base + ((c01 & 0xffffu) << 4);
    const char* s1 = base + ((c01 >> 16) << 4);
    const char* s2 = base + ((c23 & 0xffffu) << 4);
    const char* s3 = base + ((c23 >> 16) << 4);
    u32x4 a0 = *(const u32x4*)s0, b0 = *(const u32x4*)(s0 + 65536);
    u32x4 a1 = *(const u32x4*)s1, b1 = *(const u32x4*)(s1 + 65536);
    u32x4 a2 = *(const u32x4*)s2, b2 = *(const u32x4*)(s2 + 65536);
    u32x4 a3 = *(const u32x4*)s3, b3 = *(const u32x4*)(s3 + 65536);
    float w0 = w4[0], w1 = w4[1], w2 = w4[2], w3 = w4[3];
    u32 oA[4], oB[4];
#pragma unroll
    for (int e = 0; e < 4; ++e) {
      float lo = w0 * __uint_as_float(a0[e] << 16);
      lo = fmaf(w1, __uint_as_float(a1[e] << 16), lo);
      lo = fmaf(w2, __uint_as_float(a2[e] << 16), lo);
      lo = fmaf(w3, __uint_as_float(a3[e] << 16), lo);
      float hi = w0 * __uint_as_float(a0[e] & 0xffff0000u);
      hi = fmaf(w1, __uint_as_float(a1[e] & 0xffff0000u), hi);
      hi = fmaf(w2, __uint_as_float(a2[e] & 0xffff0000u), hi);
      hi = fmaf(w3, __uint_as_float(a3[e] & 0xffff0000u), hi);
      asm("v_cvt_pk_bf16_f32 %0, %1, %2" : "=v"(oA[e]) : "v"(lo), "v"(hi));
      float lo2 = w0 * __uint_as_float(b0[e] << 16);
      lo2 = fmaf(w1, __uint_as_float(b1[e] << 16), lo2);
      lo2 = fmaf(w2, __uint_as_float(b2[e] << 16), lo2);
      lo2 = fmaf(w3, __uint_as_float(b3[e] << 16), lo2);
      float hi2 = w0 * __uint_as_float(b0[e] & 0xffff0000u);
      hi2 = fmaf(w1, __uint_as_float(b1[e] & 0xffff0000u), hi2);
      hi2 = fmaf(w2, __uint_as_float(b2[e] & 0xffff0000u), hi2);
      hi2 = fmaf(w3, __uint_as_float(b3[e] & 0xffff0000u), hi2);
      asm("v_cvt_pk_bf16_f32 %0, %1, %2" : "=v"(oB[e]) : "v"(lo2), "v"(hi2));
    }
    char* dst = (char*)&ar.m.A[d][0][0] + lane * 128;
    int sw = (lane & 7) << 4;
    u32x4 vA = {oA[0], oA[1], oA[2], oA[3]};
    u32x4 vB = {oB[0], oB[1], oB[2], oB[3]};
    *(u32x4*)(dst + ((g0 << 4) ^ sw)) = vA;
    *(u32x4*)(dst + (((g0 + 1) << 4) ^ sw)) = vB;
  };

  // --- prologue ---
  u32 cur01 = 0, cur23 = 0, nxt01 = 0, nxt23 = 0;
  f32x4 curw = {0.f, 0.f, 0.f, 0.f}, nxtw = curw;
  if (!is_cons) {
    cparams(0, cur01, cur23, curw);
    stage(0, 0, 0, cur01, cur23, curw);
  }
  __syncthreads();

  // --- main loop: k rolled, cc unrolled (buffer parity = cc&1) ---
  for (int k = 0; k < 9; ++k) {
    if (!is_cons && k < 8) cparams(k + 1, nxt01, nxt23, nxtw);
#pragma unroll
    for (int cc = 0; cc < 4; ++cc) {
      const int d = cc & 1;
      if (is_cons) {
        const char* Abase = (const char*)&ar.m.A[d][0][0];
        const char* Bbase = (const char*)&ar.m.Bt[d][0];
        __builtin_amdgcn_s_setprio(1);
#pragma unroll
        for (int s = 0; s < 2; ++s) {
          int kx = (s << 6) + ((lane >> 4) << 4);
          bf16x8 a[4], bb[4];
#pragma unroll
          for (int i = 0; i < 4; ++i) {
            int r16 = (i << 4) + (lane & 15);
            a[i] = *(const bf16x8*)(Abase + r16 * 128 + (kx ^ ((r16 & 7) << 4)));
          }
#pragma unroll
          for (int j = 0; j < 4; ++j) {
            int o = obase + (j << 4) + (lane & 15);
            bb[j] = *(const bf16x8*)(Bbase + o * 128 + (kx ^ ((o & 7) << 4)));
          }
#pragma unroll
          for (int i = 0; i < 4; ++i)
#pragma unroll
            for (int j = 0; j < 4; ++j)
              acc[i][j] = __builtin_amdgcn_mfma_f32_16x16x32_bf16(a[i], bb[j], acc[i][j], 0, 0, 0);
        }
        __builtin_amdgcn_s_setprio(0);
      } else {
        int tt = (k << 2) + cc;
        if (tt < 35) {
          if (cc < 3) stage(tt + 1, cc + 1, d ^ 1, cur01, cur23, curw);
          else        stage(tt + 1, 0, d ^ 1, nxt01, nxt23, nxtw);
        }
      }
      __syncthreads();
    }
    cur01 = nxt01; cur23 = nxt23; curw = nxtw;
  }

  // --- epilogue ---
  if (is_cons) {
    // GroupNorm partial sums (D: col=lane&15 -> o, row=(lane>>4)*4+r -> px)
#pragma unroll
    for (int j = 0; j < 4; ++j) {
      float s1 = 0.f, s2 = 0.f;
#pragma unroll
      for (int i = 0; i < 4; ++i)
#pragma unroll
        for (int r = 0; r < 4; ++r) {
          float v = acc[i][j][r];
          s1 += v;
          s2 += v * v;
        }
      s1 += __shfl_xor(s1, 1, 64);  s2 += __shfl_xor(s2, 1, 64);
      s1 += __shfl_xor(s1, 2, 64);  s2 += __shfl_xor(s2, 2, 64);
      s1 += __shfl_xor(s1, 4, 64);  s2 += __shfl_xor(s2, 4, 64);
      s1 += __shfl_xor(s1, 16, 64); s2 += __shfl_xor(s2, 16, 64);
      s1 += __shfl_xor(s1, 32, 64); s2 += __shfl_xor(s2, 32, 64);
      if ((lane & 0x37) == 0) {     // lanes 0 and 8: one per 8-channel group
        int g = (obase + (j << 4) + (lane & 15)) >> 3;
        atomicAdd(&stats[((b << 5) + g) * 2 + 0], s1);
        atomicAdd(&stats[((b << 5) + g) * 2 + 1], s2);
      }
    }
    // acc -> ytile[o][px] bf16
#pragma unroll
    for (int i = 0; i < 4; ++i)
#pragma unroll
      for (int j = 0; j < 4; ++j) {
        int o = obase + (j << 4) + (lane & 15);
        int pxr = (i << 4) + ((lane >> 4) << 2);
        u32 wv0, wv1;
        asm("v_cvt_pk_bf16_f32 %0, %1, %2" : "=v"(wv0) : "v"(acc[i][j][0]), "v"(acc[i][j][1]));
        asm("v_cvt_pk_bf16_f32 %0, %1, %2" : "=v"(wv1) : "v"(acc[i][j][2]), "v"(acc[i][j][3]));
        u32x2 wv = {wv0, wv1};
        *(u32x2*)((char*)ar.ytile + o * 144 + pxr * 2) = wv;
      }
  }
  __syncthreads();
  {
    int o = t >> 1, half = t & 1;
    const char* srcb = (const char*)ar.ytile + o * 144 + (half << 6);
    unsigned short* dst = yb + (((size_t)(b * 256 + o)) << 12) + pxbase + (half << 5);
#pragma unroll
    for (int qq = 0; qq < 4; ++qq)
      *(u32x4*)((char*)dst + (qq << 4)) = *(const u32x4*)(srcb + (qq << 4));
  }
}

// ---------------------------------------------------------------------------
// K5: GroupNorm finalize + Mish — pure streaming.
// ---------------------------------------------------------------------------
__global__ __launch_bounds__(256) void gn_mish(const unsigned short* __restrict__ yb,
                                               const float* __restrict__ stats,
                                               const float* __restrict__ gamma,
                                               const float* __restrict__ beta,
                                               float* __restrict__ out) {
  int v = blockIdx.x * 512 + threadIdx.x;
#pragma unroll
  for (int it = 0; it < 2; ++it, v += 256) {
    int o = (v >> 9) & 255;
    int b = v >> 17;
    float s1 = stats[((b << 5) + (o >> 3)) * 2 + 0];
    float s2 = stats[((b << 5) + (o >> 3)) * 2 + 1];
    float mean = s1 * (1.f / 32768.f);
    float var = s2 * (1.f / 32768.f) - mean * mean;
    float rstd = rsqrtf(var + 1e-5f);
    float ga = gamma[o] * rstd, be = beta[o] - mean * gamma[o] * rstd;
    u32x4 u = *(const u32x4*)(yb + ((size_t)v << 3));
    float res[8];
#pragma unroll
    for (int e = 0; e < 4; ++e) {
      float va = __uint_as_float(u[e] << 16);
      float vb = __uint_as_float(u[e] & 0xffff0000u);
      float v0 = fmaf(va, ga, be);
      float v1 = fmaf(vb, ga, be);
      float e0 = expf(fminf(v0, 15.f));
      float e1 = expf(fminf(v1, 15.f));
      float n0 = e0 * (e0 + 2.f);
      float n1 = e1 * (e1 + 2.f);
      float m0 = v0 * (n0 / (n0 + 2.f));
      float m1 = v1 * (n1 / (n1 + 2.f));
      if (v0 > 15.f) m0 = v0;
      if (v1 > 15.f) m1 = v1;
      res[2 * e] = m0;
      res[2 * e + 1] = m1;
    }
    f32x4 o0 = {res[0], res[1], res[2], res[3]};
    f32x4 o1 = {res[4], res[5], res[6], res[7]};
    float* dst = out + ((size_t)v << 3);
    *(f32x4*)dst = o0;
    *((f32x4*)dst + 1) = o1;
  }
}

// ---------------------------------------------------------------------------
extern "C" void kernel_launch(void* const* d_in, const int* in_sizes, int n_in,
                              void* d_out, int out_size, void* d_ws, size_t ws_size,
                              hipStream_t stream) {
  const float* x     = (const float*)d_in[0];
  const float* w_off = (const float*)d_in[1];
  const float* b_off = (const float*)d_in[2];
  const float* w_dcn = (const float*)d_in[3];
  const float* gamma = (const float*)d_in[4];
  const float* beta  = (const float*)d_in[5];
  float* out = (float*)d_out;
  char* ws = (char*)d_ws;
  unsigned short* xT   = (unsigned short*)(ws);              // 16,777,216 B (bf16)
  unsigned short* yb   = (unsigned short*)(ws + 16777216);   // 16,777,216 B (bf16)
  float* offs          = (float*)(ws + 33554432);            //  2,359,296 B
  unsigned short* wT4  = (unsigned short*)(ws + 35913728);   //  1,179,648 B
  unsigned short* wOffT= (unsigned short*)(ws + 37093376);   //    147,456 B
  float* stats         = (float*)(ws + 37240832);            //      2,048 B
  prep<<<dim3(2594), dim3(256), 0, stream>>>(w_dcn, w_off, wT4, wOffT, stats);
  transpose_x<<<dim3(2048), dim3(256), 0, stream>>>(x, xT);
  conv_offset_mfma<<<dim3(256), dim3(512), 0, stream>>>(xT, wOffT, offs);
  dcn_main<<<dim3(512), dim3(512), 0, stream>>>(xT, offs, b_off, wT4, yb, stats);
  gn_mish<<<dim3(2048), dim3(256), 0, stream>>>(yb, stats, gamma, beta, out);
}

// Round 9
// 139.638 us; speedup vs baseline: 1.2271x; 1.2271x over previous
//
#include <hip/hip_runtime.h>
#include <hip/hip_bf16.h>
#include <math.h>

typedef __bf16 bf16x8 __attribute__((ext_vector_type(8)));
typedef float f32x4 __attribute__((ext_vector_type(4)));
typedef unsigned int u32;
typedef u32 u32x4 __attribute__((ext_vector_type(4)));
typedef u32 u32x2 __attribute__((ext_vector_type(2)));

// Problem constants: B=8, C=256, H=W=64, O=256, K=9, GN groups=32 (8 ch each)
// xT layout (granule-major): [b][cg=32][pix=4096][8ch] bf16; granule = 16B.

__device__ inline u32 pack2bf16(float a, float b) {
  u32 ua = __float_as_uint(a);
  u32 ub = __float_as_uint(b);
  ua += 0x7fffu + ((ua >> 16) & 1u);   // RNE
  ub += 0x7fffu + ((ub >> 16) & 1u);
  return (ua >> 16) | (ub & 0xffff0000u);
}

// ---------------------------------------------------------------------------
// K0: prep — pack w_dcn into swizzled bf16 tiles, pack w_off into swizzled
// bf16 tiles (O padded 18->32), zero stats.
// ---------------------------------------------------------------------------
__global__ void prep(const float* __restrict__ w_dcn, const float* __restrict__ w_off,
                     unsigned short* __restrict__ wT4, unsigned short* __restrict__ wOffT,
                     float* __restrict__ stats) {
  size_t id = (size_t)blockIdx.x * 256 + threadIdx.x;
  if (id < 589824) {               // 256 o * 2304 ck
    int o  = (int)(id / 2304);
    int ck = (int)(id % 2304);     // ck = k*256 + c
    int k = ck >> 8, c = ck & 255;
    float v = w_dcn[(size_t)(o * 256 + c) * 9 + k];
    u32 uv = __float_as_uint(v);
    uv += 0x7fffu + ((uv >> 16) & 1u);
    int tile = ck >> 6, kk = ck & 63;
    int lin = o * 128 + kk * 2;
    int swz = lin ^ ((o & 7) << 4);
    *(unsigned short*)((char*)wT4 + (size_t)tile * 32768 + swz) = (unsigned short)(uv >> 16);
  } else if (id < 663552) {        // 36 tiles * 32 o * 64 kk = 73728
    int r = (int)(id - 589824);
    int tile = r >> 11;            // k*4 + cc
    int rr = r & 2047;
    int o = rr >> 6, kk = rr & 63;
    int k = tile >> 2, cc = tile & 3;
    int c = (cc << 6) + kk;
    float v = (o < 18) ? w_off[(size_t)(o * 256 + c) * 9 + k] : 0.f;
    u32 uv = __float_as_uint(v);
    uv += 0x7fffu + ((uv >> 16) & 1u);
    int swz = (o * 128 + kk * 2) ^ ((o & 7) << 4);
    *(unsigned short*)((char*)wOffT + (size_t)tile * 4096 + swz) = (unsigned short)(uv >> 16);
  } else if (id < 664064) {        // zero stats: 512 floats
    stats[id - 663552] = 0.f;
  }
}

// ---------------------------------------------------------------------------
// K1: transpose x [B][C][H][W] -> xT granule-major [b][cg][pix][8ch] bf16
// ---------------------------------------------------------------------------
__global__ __launch_bounds__(256) void transpose_x(const float* __restrict__ x,
                                                   unsigned short* __restrict__ xT) {
  __shared__ float tl[64][65];
  int bx = blockIdx.x;
  int b = bx >> 8;
  int y = (bx >> 2) & 63;
  int cb = (bx & 3) << 6;          // 64-ch chunk base
  int t = threadIdx.x;
  int xi = t & 63, cr = t >> 6;
  size_t base = (((size_t)(b * 256 + cb) * 64 + y) << 6);
#pragma unroll
  for (int rep = 0; rep < 16; ++rep) {
    int cl = rep * 4 + cr;
    tl[cl][xi] = x[base + (size_t)cl * 4096 + xi];
  }
  __syncthreads();
  int xw = t & 63, cpair = t >> 6;   // cpair in [0,4)
#pragma unroll
  for (int r = 0; r < 2; ++r) {
    int cgl = cpair * 2 + r;         // local granule in this 64-ch chunk
    int cg = (cb >> 3) + cgl;
    u32 pk4[4];
#pragma unroll
    for (int i = 0; i < 4; ++i)
      pk4[i] = pack2bf16(tl[cgl * 8 + 2 * i][xw], tl[cgl * 8 + 2 * i + 1][xw]);
    u32x4 v = {pk4[0], pk4[1], pk4[2], pk4[3]};
    *(u32x4*)((char*)xT + (((size_t)b << 21)) + ((size_t)cg << 16) + ((y << 6) + xw) * 16) = v;
  }
}

// ---------------------------------------------------------------------------
// K2: offset conv via MFMA (unchanged from R7).
// ---------------------------------------------------------------------------
__global__ __launch_bounds__(512, 2) void conv_offset_mfma(
    const unsigned short* __restrict__ xT, const unsigned short* __restrict__ wOffT,
    float* __restrict__ offs) {
  __shared__ unsigned short A[2][128][64]; // 32KB, byte ^= (row&7)<<4
  __shared__ unsigned short Bo[2][2048];   // 8KB  ([32 o][64 kk], swizzled)
  const int bx = blockIdx.x;
  const int lb = ((bx & 7) << 5) + (bx >> 3);   // XCD x -> image x
  const int b = lb >> 5;
  const int rp = lb & 31;          // row pair
  const int t = threadIdx.x;
  const int lane = t & 63, wid = t >> 6;   // wid 0..7
  const char* xTbB = (const char*)xT + ((size_t)b << 21);
  const int p = t >> 2;            // local pixel 0..127
  const int row = (rp << 1) + (p >> 6);
  const int xx = p & 63;
  const int cpl = (t & 3) << 1;    // granule-pair slot within cc-chunk

  f32x4 acc[2];
  {
    f32x4 z = {0.f, 0.f, 0.f, 0.f};
    acc[0] = z; acc[1] = z;
  }

  u32x4 ra = {0u,0u,0u,0u}, rb = {0u,0u,0u,0u};

  auto issue = [&](int tt, int d) {
    int k = tt >> 2, cc = tt & 3;
    int ky = k / 3, kx = k - ky * 3;
    int ys = row - 1 + ky;
    int xs = xx - 1 + kx;
    bool ok = ((unsigned)ys < 64u) && ((unsigned)xs < 64u);
    u32x4 z = {0u,0u,0u,0u};
    ra = z; rb = z;
    if (ok) {
      const char* s0 = xTbB + ((size_t)(cc * 8 + cpl) << 16) + (((ys << 6) + xs) << 4);
      ra = *(const u32x4*)s0;
      rb = *(const u32x4*)(s0 + 65536);
    }
    if (wid < 4)
      __builtin_amdgcn_global_load_lds(
          (const __attribute__((address_space(1))) u32*)((const char*)wOffT + ((size_t)tt << 12) + (wid << 10) + (lane << 4)),
          (__attribute__((address_space(3))) u32*)((char*)&Bo[d][0] + (wid << 10)),
          16, 0, 0);
  };
  auto writeA = [&](int d) {
    char* dst = (char*)&A[d][0][0] + p * 128;
    int b0 = (t & 3) << 5;
    int sw = (p & 7) << 4;
    *(u32x4*)(dst + (b0 ^ sw)) = ra;
    *(u32x4*)(dst + ((b0 + 16) ^ sw)) = rb;
  };

  issue(0, 0);
  writeA(0);
  __syncthreads();

  int cur = 0;
  for (int tt = 0; tt < 36; ++tt) {
    if (tt < 35) issue(tt + 1, cur ^ 1);
#pragma unroll
    for (int s = 0; s < 2; ++s) {
      int r16 = (wid << 4) + (lane & 15);
      int kx = (s << 6) + ((lane >> 4) << 4);
      bf16x8 a = *(const bf16x8*)((const char*)&A[cur][0][0] + r16 * 128 + (kx ^ ((r16 & 7) << 4)));
#pragma unroll
      for (int j = 0; j < 2; ++j) {
        int o = (j << 4) + (lane & 15);
        bf16x8 bv = *(const bf16x8*)((const char*)&Bo[cur][0] + o * 128 + (kx ^ ((o & 7) << 4)));
        acc[j] = __builtin_amdgcn_mfma_f32_16x16x32_bf16(a, bv, acc[j], 0, 0, 0);
      }
    }
    if (tt < 35) writeA(cur ^ 1);
    __syncthreads();
    cur ^= 1;
  }

#pragma unroll
  for (int j = 0; j < 2; ++j) {
    int o = (j << 4) + (lane & 15);
    if (o < 18) {
#pragma unroll
      for (int r = 0; r < 4; ++r) {
        int pl = (wid << 4) + ((lane >> 4) << 2) + r;
        offs[((size_t)b * 4096 + (rp << 7) + pl) * 18 + o] = acc[j][r];
      }
    }
  }
}

// ---------------------------------------------------------------------------
// K4: main fused kernel — homogeneous waves, 2 BLOCKS/CU.
// block = 64 px x 256 O, 512 thr, 8 waves. Staging: thread = px(lane) x
// granule(wid) -> coalesced. MFMA: wave = 32px x 64o, acc[2][4] (32 regs).
// LDS exactly 80 KiB -> 2 blocks/CU = 2 anti-phased barrier domains.
// Params recomputed per-k into registers (no LDS, no role split).
// ---------------------------------------------------------------------------
union Arena {
  struct {
    unsigned short A[2][64][64];    //  16,384 B (byte ^= (row&7)<<4)
    unsigned short Bt[2][16384];    //  65,536 B ([256 o][64 kk] swz)
  } m;
  unsigned short ytile[256][72];    //  36,864 B (o-major epilogue buffer)
};

__global__ __launch_bounds__(512, 4) void dcn_main(
    const unsigned short* __restrict__ xT, const float* __restrict__ offs,
    const float* __restrict__ boff, const unsigned short* __restrict__ wT4,
    unsigned short* __restrict__ yb, float* __restrict__ stats) {
  __shared__ Arena ar;

  const int bx = blockIdx.x;
  const int lb = ((bx & 7) << 6) + (bx >> 3);   // XCD x -> image x
  const int b = lb >> 6;
  const int row = lb & 63;                      // image row
  const int pxbase = row << 6;
  const int t = threadIdx.x;
  const int lane = t & 63, wid = t >> 6;        // wid 0..7
  const char* xTbB = (const char*)xT + ((size_t)b << 21);
  const int ph = wid >> 2;                      // px half (0/1)
  const int obase = (wid & 3) << 6;             // o-block

  f32x4 acc[2][4];
#pragma unroll
  for (int i = 0; i < 2; ++i)
#pragma unroll
    for (int j = 0; j < 4; ++j) {
      f32x4 z = {0.f, 0.f, 0.f, 0.f};
      acc[i][j] = z;
    }

  // --- per-k sampling params for px = lane (registers, all waves) ---
  auto cparams = [&](int k, u32& c01, u32& c23, f32x4& w4) {
    int ky = k / 3, kx = k - ky * 3;
    const float* op = offs + ((size_t)b * 4096 + pxbase + lane) * 18 + k * 2;
    float py = op[0] + boff[k * 2] + (float)(row - 1 + ky);
    float pxf = op[1] + boff[k * 2 + 1] + (float)((lane & 63) - 1 + kx);
    float fy = floorf(py), fx = floorf(pxf);
    float dy = py - fy, dx = pxf - fx;
    int y0 = (int)fy, x0 = (int)fx;
    int y1 = y0 + 1, x1 = x0 + 1;
    float vy0 = ((unsigned)y0 < 64u) ? 1.f : 0.f;
    float vy1 = ((unsigned)y1 < 64u) ? 1.f : 0.f;
    float vx0 = ((unsigned)x0 < 64u) ? 1.f : 0.f;
    float vx1 = ((unsigned)x1 < 64u) ? 1.f : 0.f;
    int y0c = min(max(y0, 0), 63), y1c = min(max(y1, 0), 63);
    int x0c = min(max(x0, 0), 63), x1c = min(max(x1, 0), 63);
    c01 = (u32)((y0c << 6) + x0c) | ((u32)((y0c << 6) + x1c) << 16);
    c23 = (u32)((y1c << 6) + x0c) | ((u32)((y1c << 6) + x1c) << 16);
    w4[0] = (1.f - dy) * (1.f - dx) * vy0 * vx0;
    w4[1] = (1.f - dy) * dx * vy0 * vx1;
    w4[2] = dy * (1.f - dx) * vy1 * vx0;
    w4[3] = dy * dx * vy1 * vx1;
  };

  u32x4 r0, r1, r2, r3;      // in-flight sample regs (1 granule x 4 corners)

  auto issueAB = [&](int tt, int cc, int d, u32 c01, u32 c23) {
    // B: async global->LDS, 4KB slice per wave (linear, pre-swizzled src)
    {
      const char* src = (const char*)wT4 + ((size_t)tt << 15) + (wid << 12);
      char* dstb = (char*)&ar.m.Bt[d][0] + (wid << 12);
#pragma unroll
      for (int i2 = 0; i2 < 4; ++i2) {
        __builtin_amdgcn_global_load_lds(
            (const __attribute__((address_space(1))) u32*)(src + (i2 << 10) + (lane << 4)),
            (__attribute__((address_space(3))) u32*)(dstb + (i2 << 10)),
            16, 0, 0);
      }
    }
    // A: 4 corner loads of granule (cc*8 + wid) for px = lane
    const char* base = xTbB + ((size_t)((cc << 3) + wid) << 16);
    r0 = *(const u32x4*)(base + ((c01 & 0xffffu) << 4));
    r1 = *(const u32x4*)(base + ((c01 >> 16) << 4));
    r2 = *(const u32x4*)(base + ((c23 & 0xffffu) << 4));
    r3 = *(const u32x4*)(base + ((c23 >> 16) << 4));
  };
  auto packA = [&](int d, f32x4 w4) {
    float w0 = w4[0], w1 = w4[1], w2 = w4[2], w3 = w4[3];
    u32 o4[4];
#pragma unroll
    for (int e = 0; e < 4; ++e) {
      float lo = w0 * __uint_as_float(r0[e] << 16);
      lo = fmaf(w1, __uint_as_float(r1[e] << 16), lo);
      lo = fmaf(w2, __uint_as_float(r2[e] << 16), lo);
      lo = fmaf(w3, __uint_as_float(r3[e] << 16), lo);
      float hi = w0 * __uint_as_float(r0[e] & 0xffff0000u);
      hi = fmaf(w1, __uint_as_float(r1[e] & 0xffff0000u), hi);
      hi = fmaf(w2, __uint_as_float(r2[e] & 0xffff0000u), hi);
      hi = fmaf(w3, __uint_as_float(r3[e] & 0xffff0000u), hi);
      asm("v_cvt_pk_bf16_f32 %0, %1, %2" : "=v"(o4[e]) : "v"(lo), "v"(hi));
    }
    u32x4 ov = {o4[0], o4[1], o4[2], o4[3]};
    *(u32x4*)((char*)&ar.m.A[d][0][0] + lane * 128 + ((wid << 4) ^ ((lane & 7) << 4))) = ov;
  };

  // --- prologue ---
  u32 cur01, cur23, nxt01 = 0, nxt23 = 0;
  f32x4 curw, nxtw = {0.f, 0.f, 0.f, 0.f};
  cparams(0, cur01, cur23, curw);
  issueAB(0, 0, 0, cur01, cur23);
  packA(0, curw);
  __syncthreads();

  // --- main loop: k rolled, cc unrolled; step tt = k*4+cc, buffer = tt&1 ---
  for (int k = 0; k < 9; ++k) {
    if (k < 8) cparams(k + 1, nxt01, nxt23, nxtw);
#pragma unroll
    for (int cc = 0; cc < 4; ++cc) {
      const int d = cc & 1;
      const int tt = (k << 2) + cc;
      const bool last = (tt == 35);
      f32x4 pkw = (cc < 3) ? curw : nxtw;
      if (!last)
        issueAB(tt + 1, (cc + 1) & 3, d ^ 1,
                (cc < 3) ? cur01 : nxt01, (cc < 3) ? cur23 : nxt23);
      {
        const char* Abase = (const char*)&ar.m.A[d][0][0];
        const char* Bbase = (const char*)&ar.m.Bt[d][0];
        __builtin_amdgcn_s_setprio(1);
#pragma unroll
        for (int s = 0; s < 2; ++s) {
          int kx = (s << 6) + ((lane >> 4) << 4);
          bf16x8 a[2], bb[4];
#pragma unroll
          for (int i = 0; i < 2; ++i) {
            int r16 = (ph << 5) + (i << 4) + (lane & 15);
            a[i] = *(const bf16x8*)(Abase + r16 * 128 + (kx ^ ((r16 & 7) << 4)));
          }
#pragma unroll
          for (int j = 0; j < 4; ++j) {
            int o = obase + (j << 4) + (lane & 15);
            bb[j] = *(const bf16x8*)(Bbase + o * 128 + (kx ^ ((o & 7) << 4)));
          }
#pragma unroll
          for (int i = 0; i < 2; ++i)
#pragma unroll
            for (int j = 0; j < 4; ++j)
              acc[i][j] = __builtin_amdgcn_mfma_f32_16x16x32_bf16(a[i], bb[j], acc[i][j], 0, 0, 0);
        }
        __builtin_amdgcn_s_setprio(0);
      }
      __builtin_amdgcn_sched_barrier(0);
      if (!last) packA(d ^ 1, pkw);
      __syncthreads();
    }
    cur01 = nxt01; cur23 = nxt23; curw = nxtw;
  }

  // --- GroupNorm partial sums (D: col=lane&15 -> o, row=(lane>>4)*4+r -> px) ---
#pragma unroll
  for (int j = 0; j < 4; ++j) {
    float s1 = 0.f, s2 = 0.f;
#pragma unroll
    for (int i = 0; i < 2; ++i)
#pragma unroll
      for (int r = 0; r < 4; ++r) {
        float v = acc[i][j][r];
        s1 += v;
        s2 += v * v;
      }
    s1 += __shfl_xor(s1, 1, 64);  s2 += __shfl_xor(s2, 1, 64);
    s1 += __shfl_xor(s1, 2, 64);  s2 += __shfl_xor(s2, 2, 64);
    s1 += __shfl_xor(s1, 4, 64);  s2 += __shfl_xor(s2, 4, 64);
    s1 += __shfl_xor(s1, 16, 64); s2 += __shfl_xor(s2, 16, 64);
    s1 += __shfl_xor(s1, 32, 64); s2 += __shfl_xor(s2, 32, 64);
    if ((lane & 0x37) == 0) {     // lanes 0 and 8: one per 8-channel group
      int g = (obase + (j << 4) + (lane & 15)) >> 3;
      atomicAdd(&stats[((b << 5) + g) * 2 + 0], s1);
      atomicAdd(&stats[((b << 5) + g) * 2 + 1], s2);
    }
  }

  // --- acc -> ytile[o][px] bf16 ---
#pragma unroll
  for (int i = 0; i < 2; ++i)
#pragma unroll
    for (int j = 0; j < 4; ++j) {
      int o = obase + (j << 4) + (lane & 15);
      int pxr = (ph << 5) + (i << 4) + ((lane >> 4) << 2);
      u32 wv0, wv1;
      asm("v_cvt_pk_bf16_f32 %0, %1, %2" : "=v"(wv0) : "v"(acc[i][j][0]), "v"(acc[i][j][1]));
      asm("v_cvt_pk_bf16_f32 %0, %1, %2" : "=v"(wv1) : "v"(acc[i][j][2]), "v"(acc[i][j][3]));
      u32x2 wv = {wv0, wv1};
      *(u32x2*)((char*)ar.ytile + o * 144 + pxr * 2) = wv;
    }
  __syncthreads();
  {
    int o = t >> 1, half = t & 1;
    const char* srcb = (const char*)ar.ytile + o * 144 + (half << 6);
    unsigned short* dst = yb + (((size_t)(b * 256 + o)) << 12) + pxbase + (half << 5);
#pragma unroll
    for (int qq = 0; qq < 4; ++qq)
      *(u32x4*)((char*)dst + (qq << 4)) = *(const u32x4*)(srcb + (qq << 4));
  }
}

// ---------------------------------------------------------------------------
// K5: GroupNorm finalize + Mish — pure streaming.
// ---------------------------------------------------------------------------
__global__ __launch_bounds__(256) void gn_mish(const unsigned short* __restrict__ yb,
                                               const float* __restrict__ stats,
                                               const float* __restrict__ gamma,
                                               const float* __restrict__ beta,
                                               float* __restrict__ out) {
  int v = blockIdx.x * 512 + threadIdx.x;
#pragma unroll
  for (int it = 0; it < 2; ++it, v += 256) {
    int o = (v >> 9) & 255;
    int b = v >> 17;
    float s1 = stats[((b << 5) + (o >> 3)) * 2 + 0];
    float s2 = stats[((b << 5) + (o >> 3)) * 2 + 1];
    float mean = s1 * (1.f / 32768.f);
    float var = s2 * (1.f / 32768.f) - mean * mean;
    float rstd = rsqrtf(var + 1e-5f);
    float ga = gamma[o] * rstd, be = beta[o] - mean * gamma[o] * rstd;
    u32x4 u = *(const u32x4*)(yb + ((size_t)v << 3));
    float res[8];
#pragma unroll
    for (int e = 0; e < 4; ++e) {
      float va = __uint_as_float(u[e] << 16);
      float vb = __uint_as_float(u[e] & 0xffff0000u);
      float v0 = fmaf(va, ga, be);
      float v1 = fmaf(vb, ga, be);
      float e0 = expf(fminf(v0, 15.f));
      float e1 = expf(fminf(v1, 15.f));
      float n0 = e0 * (e0 + 2.f);
      float n1 = e1 * (e1 + 2.f);
      float m0 = v0 * (n0 / (n0 + 2.f));
      float m1 = v1 * (n1 / (n1 + 2.f));
      if (v0 > 15.f) m0 = v0;
      if (v1 > 15.f) m1 = v1;
      res[2 * e] = m0;
      res[2 * e + 1] = m1;
    }
    f32x4 o0 = {res[0], res[1], res[2], res[3]};
    f32x4 o1 = {res[4], res[5], res[6], res[7]};
    float* dst = out + ((size_t)v << 3);
    *(f32x4*)dst = o0;
    *((f32x4*)dst + 1) = o1;
  }
}

// ---------------------------------------------------------------------------
extern "C" void kernel_launch(void* const* d_in, const int* in_sizes, int n_in,
                              void* d_out, int out_size, void* d_ws, size_t ws_size,
                              hipStream_t stream) {
  const float* x     = (const float*)d_in[0];
  const float* w_off = (const float*)d_in[1];
  const float* b_off = (const float*)d_in[2];
  const float* w_dcn = (const float*)d_in[3];
  const float* gamma = (const float*)d_in[4];
  const float* beta  = (const float*)d_in[5];
  float* out = (float*)d_out;
  char* ws = (char*)d_ws;
  unsigned short* xT   = (unsigned short*)(ws);              // 16,777,216 B (bf16)
  unsigned short* yb   = (unsigned short*)(ws + 16777216);   // 16,777,216 B (bf16)
  float* offs          = (float*)(ws + 33554432);            //  2,359,296 B
  unsigned short* wT4  = (unsigned short*)(ws + 35913728);   //  1,179,648 B
  unsigned short* wOffT= (unsigned short*)(ws + 37093376);   //    147,456 B
  float* stats         = (float*)(ws + 37240832);            //      2,048 B
  prep<<<dim3(2594), dim3(256), 0, stream>>>(w_dcn, w_off, wT4, wOffT, stats);
  transpose_x<<<dim3(2048), dim3(256), 0, stream>>>(x, xT);
  conv_offset_mfma<<<dim3(256), dim3(512), 0, stream>>>(xT, wOffT, offs);
  dcn_main<<<dim3(512), dim3(512), 0, stream>>>(xT, offs, b_off, wT4, yb, stats);
  gn_mish<<<dim3(2048), dim3(256), 0, stream>>>(yb, stats, gamma, beta, out);
}